// Round 9
// baseline (919.823 us; speedup 1.0000x reference)
//
#include <hip/hip_runtime.h>

#define OUT0 8388608   // N*F floats: start of ST region in d_out

typedef __attribute__((ext_vector_type(8))) short sh8;
typedef __attribute__((ext_vector_type(4))) short sh4;
typedef __attribute__((ext_vector_type(4))) float fl4;

__device__ __forceinline__ unsigned short f2bf(float f) {
    unsigned int u = __builtin_bit_cast(unsigned int, f);
    u += 0x7FFFu + ((u >> 16) & 1u);               // round-to-nearest-even
    return (unsigned short)(u >> 16);
}
__device__ __forceinline__ unsigned int cvt2u(float a, float b) {
    return (unsigned int)f2bf(a) | ((unsigned int)f2bf(b) << 16);
}
__device__ __forceinline__ float bf2f(unsigned short s) {
    unsigned int u = ((unsigned int)s) << 16;
    return __builtin_bit_cast(float, u);
}

template<int N>
__device__ __forceinline__ void vmwait() {
    asm volatile("s_waitcnt vmcnt(%0)" :: "n"(N) : "memory");
    __builtin_amdgcn_sched_barrier(0);             // rule #18: pin consumers below
}

// [32 rows][256 cols] bf16 tile, XOR-swizzled for conflict-free ds_read_b128
#define EA(r,c) (((r)<<8) + ((c) ^ (((r)&7)<<3)))
// v_T tile [256 chan][32 rows]
#define EV(c,r) (((c)<<5) + ((r) ^ (((c)&3)<<3)))

// W pre-swizzled to MFMA-fragment order: wsW[mat][ct(16)][kb(8)][lane(64)][j(8)]
__global__ void setup_kernel(const float* __restrict__ Wq, const float* __restrict__ Wk,
                             const float* __restrict__ Wv, const float* __restrict__ lw,
                             unsigned short* __restrict__ wsW) {
    int tid = blockIdx.x * blockDim.x + threadIdx.x;   // 65536 threads
    int ct = tid >> 12, kb = (tid >> 9) & 7, l = (tid >> 3) & 63, j = tid & 7;
    int col = ct * 16 + (l & 15);
    int k   = kb * 32 + (l >> 4) * 8 + j;
    wsW[tid]          = f2bf(Wq[k * 256 + col]);   // B[k][col] of Wq
    wsW[65536 + tid]  = f2bf(Wk[k * 256 + col]);
    wsW[131072 + tid] = f2bf(Wv[k * 256 + col]);
    wsW[196608 + tid] = f2bf(lw[col * 256 + k]);   // B[k][col] of lin_w^T
}

// acc[4][2] += A(lds [32][256]) @ W(global bf16, fragment order); wave w: cols w*64..+63
// Depth-4 rolling B-prefetch via asm volatile (compiler cannot sink) + counted vmcnt:
// 16-20 dwordx4 in flight -> L2 latency hidden under MFMAs.
__device__ __forceinline__ void gemm32x256(const unsigned short* A,
                                           const unsigned short* __restrict__ W,
                                           int w, int l, fl4 acc[4][2]) {
    const int qd = l >> 4, c16 = l & 15;
    const unsigned short* Wb = W + w * 16384 + l * 8;   // (w*4 colTiles)*4096
    sh8 bfr[8][4];
#pragma unroll
    for (int kb = 0; kb < 4; ++kb)                 // prologue: 16 loads in flight
#pragma unroll
        for (int ci = 0; ci < 4; ++ci)
            asm volatile("global_load_dwordx4 %0, %1, off"
                         : "=v"(bfr[kb][ci]) : "v"(Wb + ci * 4096 + kb * 512));
    sh8 afr[2][2];
#pragma unroll
    for (int rt = 0; rt < 2; ++rt)
        afr[0][rt] = *(const sh8*)(A + EA(rt * 16 + c16, qd * 8));
#pragma unroll
    for (int kb = 0; kb < 8; ++kb) {
        const int cur = kb & 1, nxt = cur ^ 1;      // kb unrolled -> static idx
        if (kb < 4)                                // rolling issue: kb+4
#pragma unroll
            for (int ci = 0; ci < 4; ++ci)
                asm volatile("global_load_dwordx4 %0, %1, off"
                             : "=v"(bfr[kb + 4][ci]) : "v"(Wb + ci * 4096 + (kb + 4) * 512));
        if (kb < 7)
#pragma unroll
            for (int rt = 0; rt < 2; ++rt)
                afr[nxt][rt] = *(const sh8*)(A + EA(rt * 16 + c16, (kb + 1) * 32 + qd * 8));
        // wait for bfr[kb] (4 frags): issued_total - 4*(kb+1) outstanding allowed
        if      (kb == 0) vmwait<16>();
        else if (kb == 1) vmwait<16>();
        else if (kb == 2) vmwait<16>();
        else if (kb == 3) vmwait<16>();
        else if (kb == 4) vmwait<12>();
        else if (kb == 5) vmwait<8>();
        else if (kb == 6) vmwait<4>();
        else              vmwait<0>();
#pragma unroll
        for (int ci = 0; ci < 4; ++ci)
#pragma unroll
            for (int rt = 0; rt < 2; ++rt)
                acc[ci][rt] = __builtin_amdgcn_mfma_f32_16x16x32_bf16(
                    afr[cur][rt], bfr[kb][ci], acc[ci][rt], 0, 0, 0);
    }
}

__launch_bounds__(256, 3)
__global__ void fused_kernel(const float* __restrict__ inputs, const float* __restrict__ EC,
                             const float* __restrict__ pos_emb, const float* __restrict__ lin_b,
                             const unsigned short* __restrict__ wsW,
                             float* __restrict__ d_out) {
    extern __shared__ char smem[];
    unsigned short* X = (unsigned short*)smem;   // temporal -> v_T      [32][256] / [256][32]
    unsigned short* Y = X + 8192;                // EC -> k -> P(ST lay) [32][256]
    unsigned short* Z = Y + 8192;                // q -> ctx             [32][256]
    float*       outL = (float*)(Z + 8192);      // [2][256] f32

    const int tid = threadIdx.x;
    const int w = tid >> 6, l = tid & 63;
    const int qd = l >> 4, c16 = l & 15;
    const size_t rbase = (size_t)blockIdx.x * 32;
    const int n0 = blockIdx.x * 2;

    // ---- stage: issue ALL global loads first (one HBM round-trip), then convert ----
    fl4 ins[8], ecs[8], pes[8];
#pragma unroll
    for (int i = 0; i < 8; ++i) {
        size_t g = (rbase + i * 4 + w) * 256 + 4 * l;
        ins[i] = *(const fl4*)(inputs + g);
        ecs[i] = *(const fl4*)(EC + g);
    }
#pragma unroll
    for (int i = 0; i < 8; ++i)
        pes[i] = *(const fl4*)(pos_emb + ((i * 4 + w) & 15) * 256 + 4 * l);

    // zero outL (tmean/ctx-mean accumulate via LDS atomics after B1)
    outL[tid] = 0.f;
    outL[256 + tid] = 0.f;

    fl4 tacc0 = {0.f, 0.f, 0.f, 0.f}, tacc1 = {0.f, 0.f, 0.f, 0.f};
#pragma unroll
    for (int i = 0; i < 8; ++i) {
        int row = i * 4 + w;
        fl4 t4 = ins[i] + pes[i];
        if (i < 4) tacc0 += t4; else tacc1 += t4;
        *(uint2*)(X + EA(row, 4 * l)) = make_uint2(cvt2u(t4[0], t4[1]), cvt2u(t4[2], t4[3]));
        *(uint2*)(Y + EA(row, 4 * l)) =
            make_uint2(cvt2u(ecs[i][0], ecs[i][1]), cvt2u(ecs[i][2], ecs[i][3]));
    }
    __syncthreads();                               // B1

    // tmean contribution (rows w,4+w,8+w,12+w -> node0; +16 -> node1)
#pragma unroll
    for (int j = 0; j < 4; ++j) {
        atomicAdd(&outL[4 * l + j], tacc0[j] * 0.0625f);
        atomicAdd(&outL[256 + 4 * l + j], tacc1[j] * 0.0625f);
    }

    // ---- k = EC@Wk (in-place to Y), q = temporal@Wq (to Z) ----
    {
        fl4 aK[4][2] = {}, aQ[4][2] = {};
        gemm32x256(Y, wsW + 65536, w, l, aK);
        gemm32x256(X, wsW, w, l, aQ);
        __syncthreads();                           // B2: all X/Y reads done
#pragma unroll
        for (int ci = 0; ci < 4; ++ci) {
            int col = w * 64 + ci * 16 + c16;
#pragma unroll
            for (int rt = 0; rt < 2; ++rt) {
                int r0 = rt * 16 + qd * 4;
                unsigned int k01 = cvt2u(aK[ci][rt][0], aK[ci][rt][1]);
                unsigned int k23 = cvt2u(aK[ci][rt][2], aK[ci][rt][3]);
                unsigned int q01 = cvt2u(aQ[ci][rt][0], aQ[ci][rt][1]);
                unsigned int q23 = cvt2u(aQ[ci][rt][2], aQ[ci][rt][3]);
                Y[EA(r0 + 0, col)] = (unsigned short)k01;
                Y[EA(r0 + 1, col)] = (unsigned short)(k01 >> 16);
                Y[EA(r0 + 2, col)] = (unsigned short)k23;
                Y[EA(r0 + 3, col)] = (unsigned short)(k23 >> 16);
                Z[EA(r0 + 0, col)] = (unsigned short)q01;
                Z[EA(r0 + 1, col)] = (unsigned short)(q01 >> 16);
                Z[EA(r0 + 2, col)] = (unsigned short)q23;
                Z[EA(r0 + 3, col)] = (unsigned short)(q23 >> 16);
            }
        }
    }
    __syncthreads();                               // B3: k,q ready

    // ---- QK^T transposed: st[h] = K @ Q^T -> lane holds S[qt=c16][kt=qd*4+i2] ----
    const int nd = w >> 1, hb = (w & 1) * 8;
    fl4 st[8];
#pragma unroll
    for (int h = 0; h < 8; ++h) {
        sh8 ka = {}, qa = {};
        if (l < 32) {                              // d-dim K=16 padded to 32
            ka = *(const sh8*)(Y + EA(nd * 16 + c16, (hb + h) * 16 + qd * 8));
            qa = *(const sh8*)(Z + EA(nd * 16 + c16, (hb + h) * 16 + qd * 8));
        }
        fl4 z = {};
        st[h] = __builtin_amdgcn_mfma_f32_16x16x32_bf16(ka, qa, z, 0, 0, 0);
    }

    // ---- v = temporal@Wv (overlaps softmax below) ----
    fl4 aV[4][2] = {};
    gemm32x256(X, wsW + 131072, w, l, aV);

    // ---- softmax over kt: 3 in-lane adds + 2 shfl; no max-subtract (f32 exp headroom) ----
#pragma unroll
    for (int h = 0; h < 8; ++h) {
        fl4 e;
#pragma unroll
        for (int i2 = 0; i2 < 4; ++i2)
            e[i2] = __builtin_amdgcn_exp2f(st[h][i2] * 0.36067376022f);  // exp(s*0.25)
        float sum = e[0] + e[1] + e[2] + e[3];
        sum += __shfl_xor(sum, 16);
        sum += __shfl_xor(sum, 32);
        float r = __builtin_amdgcn_rcpf(sum);
        // P in ST layout: row = node*16+qt, cols h*16 + qd*4 + i2 (contiguous 4)
        *(uint2*)(Y + EA(nd * 16 + c16, (hb + h) * 16 + qd * 4)) =
            make_uint2(cvt2u(e[0] * r, e[1] * r), cvt2u(e[2] * r, e[3] * r));
    }
    __syncthreads();                               // B4: X reads (v GEMM) done, P written

    // ---- v_T -> X (t contiguous per i2 -> uint2 stores) ----
#pragma unroll
    for (int ci = 0; ci < 4; ++ci) {
        int col = w * 64 + ci * 16 + c16;
#pragma unroll
        for (int rt = 0; rt < 2; ++rt) {
            int t0 = rt * 16 + qd * 4;
            *(uint2*)(X + EV(col, t0)) =
                make_uint2(cvt2u(aV[ci][rt][0], aV[ci][rt][1]),
                           cvt2u(aV[ci][rt][2], aV[ci][rt][3]));
        }
    }
    __syncthreads();                               // B5: P, v_T ready

    // ---- PV: ctx -> Z (q dead); fold ctx-mean into outL ----
#pragma unroll
    for (int h = 0; h < 8; ++h) {
        sh8 pa = {};
        if (l < 32)                                // kt 16..31 pad = zero
            pa = *(const sh8*)(Y + EA(nd * 16 + c16, (hb + h) * 16 + qd * 8));
        sh8 vb = *(const sh8*)(X + EV((hb + h) * 16 + c16, nd * 16 + (qd & 1) * 8));
        fl4 z = {};
        fl4 cx = __builtin_amdgcn_mfma_f32_16x16x32_bf16(pa, vb, z, 0, 0, 0);
        int col = (hb + h) * 16 + c16;
        unsigned int c01 = cvt2u(cx[0], cx[1]);
        unsigned int c23 = cvt2u(cx[2], cx[3]);
        int r0 = nd * 16 + qd * 4;
        Z[EA(r0 + 0, col)] = (unsigned short)c01;
        Z[EA(r0 + 1, col)] = (unsigned short)(c01 >> 16);
        Z[EA(r0 + 2, col)] = (unsigned short)c23;
        Z[EA(r0 + 3, col)] = (unsigned short)(c23 >> 16);
        atomicAdd(&outL[nd * 256 + col], (cx[0] + cx[1] + cx[2] + cx[3]) * 0.0625f);
    }

    // ---- ST dump: Y is [node][qt][h*16+kt] => coalesced fl4 stores ----
#pragma unroll
    for (int ch = 0; ch < 8; ++ch) {
        int flat = ch * 1024 + tid * 4;
        int row = flat >> 8, col = flat & 255;
        sh4 pv = *(const sh4*)(Y + (row << 8) + (col ^ ((row & 7) << 3)));
        fl4 o;
#pragma unroll
        for (int j = 0; j < 4; ++j) o[j] = bf2f((unsigned short)pv[j]);
        *(fl4*)(d_out + OUT0 + (size_t)blockIdx.x * 8192 + flat) = o;
    }
    __syncthreads();                               // B6: ctx(Z) ready

    // ---- ff = relu(ctx@lin_w^T + b); mean over T into outL (ctx-mean already added) ----
    {
        fl4 aF[4][2] = {};
        gemm32x256(Z, wsW + 196608, w, l, aF);
#pragma unroll
        for (int ci = 0; ci < 4; ++ci) {
            int col = w * 64 + ci * 16 + c16;
            float bias = lin_b[col];
#pragma unroll
            for (int rt = 0; rt < 2; ++rt) {
                float ssum = 0.f;
#pragma unroll
                for (int i2 = 0; i2 < 4; ++i2)
                    ssum += fmaxf(aF[ci][rt][i2] + bias, 0.f);
                ssum += __shfl_xor(ssum, 16);      // sum 4 qd row-groups -> all 16 t
                ssum += __shfl_xor(ssum, 32);
                if (l < 16) outL[rt * 256 + col] += ssum * 0.0625f;
            }
        }
    }
    __syncthreads();                               // B7

    // ---- write out[n][c] ----
    if (tid < 128) {
        int idx = tid * 4;
        fl4 o = *(const fl4*)(outL + idx);
        *(fl4*)(d_out + (size_t)n0 * 256 + idx) = o;
    }
}

extern "C" void kernel_launch(void* const* d_in, const int* in_sizes, int n_in,
                              void* d_out, int out_size, void* d_ws, size_t ws_size,
                              hipStream_t stream) {
    const float* inputs = (const float*)d_in[0];
    const float* EC     = (const float*)d_in[1];
    const float* pos    = (const float*)d_in[2];
    const float* Wq     = (const float*)d_in[3];
    const float* Wk     = (const float*)d_in[4];
    const float* Wv     = (const float*)d_in[5];
    const float* lw     = (const float*)d_in[6];
    const float* lb     = (const float*)d_in[7];
    unsigned short* wsW = (unsigned short*)d_ws;   // 4 x 65536 bf16 = 512 KB
    float* out = (float*)d_out;

    (void)hipFuncSetAttribute(reinterpret_cast<const void*>(fused_kernel),
                              hipFuncAttributeMaxDynamicSharedMemorySize, 51200);

    setup_kernel<<<256, 256, 0, stream>>>(Wq, Wk, Wv, lw, wsW);
    fused_kernel<<<16384, 256, 51200, stream>>>(inputs, EC, pos, lb, wsW, out);
}

// Round 10
// 776.875 us; speedup vs baseline: 1.1840x; 1.1840x over previous
//
#include <hip/hip_runtime.h>

#define OUT0 8388608   // N*F floats: start of ST region in d_out

typedef __attribute__((ext_vector_type(8))) short sh8;
typedef __attribute__((ext_vector_type(4))) short sh4;
typedef __attribute__((ext_vector_type(4))) float fl4;

__device__ __forceinline__ unsigned short f2bf(float f) {
    unsigned int u = __builtin_bit_cast(unsigned int, f);
    u += 0x7FFFu + ((u >> 16) & 1u);               // round-to-nearest-even
    return (unsigned short)(u >> 16);
}
__device__ __forceinline__ unsigned int cvt2u(float a, float b) {
    return (unsigned int)f2bf(a) | ((unsigned int)f2bf(b) << 16);
}
__device__ __forceinline__ float bf2f(unsigned short s) {
    unsigned int u = ((unsigned int)s) << 16;
    return __builtin_bit_cast(float, u);
}

// [32 rows][256 cols] bf16 tile, XOR-swizzled for conflict-free ds_read_b128
#define EA(r,c) (((r)<<8) + ((c) ^ (((r)&7)<<3)))
// v_T tile [256 chan][32 rows]
#define EV(c,r) (((c)<<5) + ((r) ^ (((c)&3)<<3)))

// W pre-swizzled to MFMA-fragment order: wsW[mat][ct(16)][kb(8)][lane(64)][j(8)]
__global__ void setup_kernel(const float* __restrict__ Wq, const float* __restrict__ Wk,
                             const float* __restrict__ Wv, const float* __restrict__ lw,
                             unsigned short* __restrict__ wsW) {
    int tid = blockIdx.x * blockDim.x + threadIdx.x;   // 65536 threads
    int ct = tid >> 12, kb = (tid >> 9) & 7, l = (tid >> 3) & 63, j = tid & 7;
    int col = ct * 16 + (l & 15);
    int k   = kb * 32 + (l >> 4) * 8 + j;
    wsW[tid]          = f2bf(Wq[k * 256 + col]);   // B[k][col] of Wq
    wsW[65536 + tid]  = f2bf(Wk[k * 256 + col]);
    wsW[131072 + tid] = f2bf(Wv[k * 256 + col]);
    wsW[196608 + tid] = f2bf(lw[col * 256 + k]);   // B[k][col] of lin_w^T
}

// acc[4][2] += A(lds [32][256]) @ W(global bf16, fragment order); wave w: cols w*64..+63
// 4-slot rolling B-prefetch (issue kb+3): ~12 dwordx4 in flight, fits the 170-VGPR cap
// of launch_bounds(256,3) so the compiler neither sinks (r8) nor spills (r9) it.
__device__ __forceinline__ void gemm32x256(const unsigned short* A,
                                           const unsigned short* __restrict__ W,
                                           int w, int l, fl4 acc[4][2]) {
    const int qd = l >> 4, c16 = l & 15;
    const unsigned short* Wb = W + w * 16384 + l * 8;   // (w*4 colTiles)*4096
    sh8 bfr[4][4];
#pragma unroll
    for (int kb = 0; kb < 3; ++kb)                 // prologue: 12 loads in flight
#pragma unroll
        for (int ci = 0; ci < 4; ++ci)
            bfr[kb][ci] = *(const sh8*)(Wb + ci * 4096 + kb * 512);
    sh8 afr[2][2];
#pragma unroll
    for (int rt = 0; rt < 2; ++rt)
        afr[0][rt] = *(const sh8*)(A + EA(rt * 16 + c16, qd * 8));
#pragma unroll
    for (int kb = 0; kb < 8; ++kb) {
        const int cur = kb & 3, nxt = (kb + 3) & 3, ab = kb & 1;  // static (unrolled)
        if (kb < 5)                                // rolling issue: kb+3
#pragma unroll
            for (int ci = 0; ci < 4; ++ci)
                bfr[nxt][ci] = *(const sh8*)(Wb + ci * 4096 + (kb + 3) * 512);
        if (kb < 7)
#pragma unroll
            for (int rt = 0; rt < 2; ++rt)
                afr[ab ^ 1][rt] = *(const sh8*)(A + EA(rt * 16 + c16, (kb + 1) * 32 + qd * 8));
        __builtin_amdgcn_s_setprio(1);             // T5: favor MFMA wave on CU scheduler
#pragma unroll
        for (int ci = 0; ci < 4; ++ci)
#pragma unroll
            for (int rt = 0; rt < 2; ++rt)
                acc[ci][rt] = __builtin_amdgcn_mfma_f32_16x16x32_bf16(
                    afr[ab][rt], bfr[cur][ci], acc[ci][rt], 0, 0, 0);
        __builtin_amdgcn_s_setprio(0);
    }
}

__launch_bounds__(256, 3)
__global__ void fused_kernel(const float* __restrict__ inputs, const float* __restrict__ EC,
                             const float* __restrict__ pos_emb, const float* __restrict__ lin_b,
                             const unsigned short* __restrict__ wsW,
                             float* __restrict__ d_out) {
    extern __shared__ char smem[];
    unsigned short* X = (unsigned short*)smem;   // temporal -> v_T      [32][256] / [256][32]
    unsigned short* Y = X + 8192;                // EC -> k -> P         [32][256]
    unsigned short* Z = Y + 8192;                // q -> ctx             [32][256]
    float*       outL = (float*)(Z + 8192);      // [2][256] f32

    const int tid = threadIdx.x;
    const int w = tid >> 6, l = tid & 63;
    const int qd = l >> 4, c16 = l & 15;
    const size_t rbase = (size_t)blockIdx.x * 32;
    const int n0 = blockIdx.x * 2;

    // ---- stage: issue ALL global loads first (one HBM round-trip), then convert ----
    fl4 ins[8], ecs[8], pes[8];
#pragma unroll
    for (int i = 0; i < 8; ++i) {
        size_t g = (rbase + i * 4 + w) * 256 + 4 * l;
        ins[i] = *(const fl4*)(inputs + g);
        ecs[i] = *(const fl4*)(EC + g);
    }
#pragma unroll
    for (int i = 0; i < 8; ++i)
        pes[i] = *(const fl4*)(pos_emb + ((i * 4 + w) & 15) * 256 + 4 * l);

    // zero outL (tmean/ctx-mean accumulate via LDS atomics after B1)
    outL[tid] = 0.f;
    outL[256 + tid] = 0.f;

    fl4 tacc0 = {0.f, 0.f, 0.f, 0.f}, tacc1 = {0.f, 0.f, 0.f, 0.f};
#pragma unroll
    for (int i = 0; i < 8; ++i) {
        int row = i * 4 + w;
        fl4 t4 = ins[i] + pes[i];
        if (i < 4) tacc0 += t4; else tacc1 += t4;
        *(uint2*)(X + EA(row, 4 * l)) = make_uint2(cvt2u(t4[0], t4[1]), cvt2u(t4[2], t4[3]));
        *(uint2*)(Y + EA(row, 4 * l)) =
            make_uint2(cvt2u(ecs[i][0], ecs[i][1]), cvt2u(ecs[i][2], ecs[i][3]));
    }
    __syncthreads();                               // B1

    // tmean contribution (rows w,4+w,8+w,12+w -> node0; +16 -> node1)
#pragma unroll
    for (int j = 0; j < 4; ++j) {
        atomicAdd(&outL[4 * l + j], tacc0[j] * 0.0625f);
        atomicAdd(&outL[256 + 4 * l + j], tacc1[j] * 0.0625f);
    }

    // ---- k = EC@Wk (in-place to Y), q = temporal@Wq (to Z) ----
    {
        fl4 aK[4][2] = {}, aQ[4][2] = {};
        gemm32x256(Y, wsW + 65536, w, l, aK);
        gemm32x256(X, wsW, w, l, aQ);
        __syncthreads();                           // B2: all X/Y reads done
#pragma unroll
        for (int ci = 0; ci < 4; ++ci) {
            int col = w * 64 + ci * 16 + c16;
#pragma unroll
            for (int rt = 0; rt < 2; ++rt) {
                int r0 = rt * 16 + qd * 4;
                unsigned int k01 = cvt2u(aK[ci][rt][0], aK[ci][rt][1]);
                unsigned int k23 = cvt2u(aK[ci][rt][2], aK[ci][rt][3]);
                unsigned int q01 = cvt2u(aQ[ci][rt][0], aQ[ci][rt][1]);
                unsigned int q23 = cvt2u(aQ[ci][rt][2], aQ[ci][rt][3]);
                Y[EA(r0 + 0, col)] = (unsigned short)k01;
                Y[EA(r0 + 1, col)] = (unsigned short)(k01 >> 16);
                Y[EA(r0 + 2, col)] = (unsigned short)k23;
                Y[EA(r0 + 3, col)] = (unsigned short)(k23 >> 16);
                Z[EA(r0 + 0, col)] = (unsigned short)q01;
                Z[EA(r0 + 1, col)] = (unsigned short)(q01 >> 16);
                Z[EA(r0 + 2, col)] = (unsigned short)q23;
                Z[EA(r0 + 3, col)] = (unsigned short)(q23 >> 16);
            }
        }
    }
    __syncthreads();                               // B3: k,q ready

    // ---- QK^T transposed: st[h] = K @ Q^T -> lane holds S[qt=c16][kt=qd*4+i2] ----
    const int nd = w >> 1, hb = (w & 1) * 8;
    fl4 st[8];
    __builtin_amdgcn_s_setprio(1);
#pragma unroll
    for (int h = 0; h < 8; ++h) {
        sh8 ka = {}, qa = {};
        if (l < 32) {                              // d-dim K=16 padded to 32
            ka = *(const sh8*)(Y + EA(nd * 16 + c16, (hb + h) * 16 + qd * 8));
            qa = *(const sh8*)(Z + EA(nd * 16 + c16, (hb + h) * 16 + qd * 8));
        }
        fl4 z = {};
        st[h] = __builtin_amdgcn_mfma_f32_16x16x32_bf16(ka, qa, z, 0, 0, 0);
    }
    __builtin_amdgcn_s_setprio(0);

    // ---- v = temporal@Wv (overlaps softmax below) ----
    fl4 aV[4][2] = {};
    gemm32x256(X, wsW + 131072, w, l, aV);

    // ---- softmax over kt (3 adds + 2 shfl) + DIRECT ST store from regs + P->LDS ----
    const size_t STb = (size_t)OUT0 + (size_t)(n0 + nd) * 4096
                     + (size_t)c16 * 256 + hb * 16 + qd * 4;
#pragma unroll
    for (int h = 0; h < 8; ++h) {
        fl4 e;
#pragma unroll
        for (int i2 = 0; i2 < 4; ++i2)
            e[i2] = __builtin_amdgcn_exp2f(st[h][i2] * 0.36067376022f);  // exp(s*0.25)
        float sum = e[0] + e[1] + e[2] + e[3];
        sum += __shfl_xor(sum, 16);
        sum += __shfl_xor(sum, 32);
        float r = __builtin_amdgcn_rcpf(sum);
        fl4 p = {e[0] * r, e[1] * r, e[2] * r, e[3] * r};
        *(fl4*)(d_out + STb + h * 16) = p;         // ST[n][qt=c16][hb+h][kt=qd*4+i2]
        *(uint2*)(Y + EA(nd * 16 + c16, (hb + h) * 16 + qd * 4)) =
            make_uint2(cvt2u(p[0], p[1]), cvt2u(p[2], p[3]));
    }
    __syncthreads();                               // B4: X reads (v GEMM) done, P written

    // ---- v_T -> X (t contiguous per i2 -> uint2 stores) ----
#pragma unroll
    for (int ci = 0; ci < 4; ++ci) {
        int col = w * 64 + ci * 16 + c16;
#pragma unroll
        for (int rt = 0; rt < 2; ++rt) {
            int t0 = rt * 16 + qd * 4;
            *(uint2*)(X + EV(col, t0)) =
                make_uint2(cvt2u(aV[ci][rt][0], aV[ci][rt][1]),
                           cvt2u(aV[ci][rt][2], aV[ci][rt][3]));
        }
    }
    __syncthreads();                               // B5: P, v_T ready

    // ---- PV: ctx -> Z (q dead); fold ctx-mean into outL ----
#pragma unroll
    for (int h = 0; h < 8; ++h) {
        sh8 pa = {};
        if (l < 32)                                // kt 16..31 pad = zero
            pa = *(const sh8*)(Y + EA(nd * 16 + c16, (hb + h) * 16 + qd * 8));
        sh8 vb = *(const sh8*)(X + EV((hb + h) * 16 + c16, nd * 16 + (qd & 1) * 8));
        fl4 z = {};
        __builtin_amdgcn_s_setprio(1);
        fl4 cx = __builtin_amdgcn_mfma_f32_16x16x32_bf16(pa, vb, z, 0, 0, 0);
        __builtin_amdgcn_s_setprio(0);
        int col = (hb + h) * 16 + c16;
        unsigned int c01 = cvt2u(cx[0], cx[1]);
        unsigned int c23 = cvt2u(cx[2], cx[3]);
        int r0 = nd * 16 + qd * 4;
        Z[EA(r0 + 0, col)] = (unsigned short)c01;
        Z[EA(r0 + 1, col)] = (unsigned short)(c01 >> 16);
        Z[EA(r0 + 2, col)] = (unsigned short)c23;
        Z[EA(r0 + 3, col)] = (unsigned short)(c23 >> 16);
        atomicAdd(&outL[nd * 256 + col], (cx[0] + cx[1] + cx[2] + cx[3]) * 0.0625f);
    }
    __syncthreads();                               // B6: ctx(Z) ready

    // ---- ff = relu(ctx@lin_w^T + b); mean over T into outL (ctx-mean already added) ----
    {
        fl4 aF[4][2] = {};
        gemm32x256(Z, wsW + 196608, w, l, aF);
#pragma unroll
        for (int ci = 0; ci < 4; ++ci) {
            int col = w * 64 + ci * 16 + c16;
            float bias = lin_b[col];
#pragma unroll
            for (int rt = 0; rt < 2; ++rt) {
                float ssum = 0.f;
#pragma unroll
                for (int i2 = 0; i2 < 4; ++i2)
                    ssum += fmaxf(aF[ci][rt][i2] + bias, 0.f);
                ssum += __shfl_xor(ssum, 16);      // sum 4 qd row-groups -> all 16 t
                ssum += __shfl_xor(ssum, 32);
                if (l < 16) outL[rt * 256 + col] += ssum * 0.0625f;
            }
        }
    }
    __syncthreads();                               // B7

    // ---- write out[n][c] ----
    if (tid < 128) {
        int idx = tid * 4;
        fl4 o = *(const fl4*)(outL + idx);
        *(fl4*)(d_out + (size_t)n0 * 256 + idx) = o;
    }
}

extern "C" void kernel_launch(void* const* d_in, const int* in_sizes, int n_in,
                              void* d_out, int out_size, void* d_ws, size_t ws_size,
                              hipStream_t stream) {
    const float* inputs = (const float*)d_in[0];
    const float* EC     = (const float*)d_in[1];
    const float* pos    = (const float*)d_in[2];
    const float* Wq     = (const float*)d_in[3];
    const float* Wk     = (const float*)d_in[4];
    const float* Wv     = (const float*)d_in[5];
    const float* lw     = (const float*)d_in[6];
    const float* lb     = (const float*)d_in[7];
    unsigned short* wsW = (unsigned short*)d_ws;   // 4 x 65536 bf16 = 512 KB
    float* out = (float*)d_out;

    (void)hipFuncSetAttribute(reinterpret_cast<const void*>(fused_kernel),
                              hipFuncAttributeMaxDynamicSharedMemorySize, 51200);

    setup_kernel<<<256, 256, 0, stream>>>(Wq, Wk, Wv, lw, wsW);
    fused_kernel<<<16384, 256, 51200, stream>>>(inputs, EC, pos, lb, wsW, out);
}

// Round 11
// 663.320 us; speedup vs baseline: 1.3867x; 1.1712x over previous
//
#include <hip/hip_runtime.h>

#define OUT0 8388608   // N*F floats: start of ST region in d_out

typedef __attribute__((ext_vector_type(8))) short sh8;
typedef __attribute__((ext_vector_type(4))) short sh4;
typedef __attribute__((ext_vector_type(4))) float fl4;

__device__ __forceinline__ unsigned short f2bf(float f) {
    unsigned int u = __builtin_bit_cast(unsigned int, f);
    u += 0x7FFFu + ((u >> 16) & 1u);               // round-to-nearest-even
    return (unsigned short)(u >> 16);
}
__device__ __forceinline__ unsigned int cvt2u(float a, float b) {
    return (unsigned int)f2bf(a) | ((unsigned int)f2bf(b) << 16);
}
__device__ __forceinline__ float bf2f(unsigned short s) {
    unsigned int u = ((unsigned int)s) << 16;
    return __builtin_bit_cast(float, u);
}

template<int N>
__device__ __forceinline__ void vmwait() {
    asm volatile("s_waitcnt vmcnt(%0)" :: "n"(N) : "memory");
    __builtin_amdgcn_sched_barrier(0);             // rule #18: MFMAs must not hoist above
}

// [32 rows][256 cols] bf16 tile, XOR-swizzled for conflict-free ds_read_b128
#define EA(r,c) (((r)<<8) + ((c) ^ (((r)&7)<<3)))
// v_T tile [256 chan][32 rows]
#define EV(c,r) (((c)<<5) + ((r) ^ (((c)&3)<<3)))

// W pre-swizzled to MFMA-fragment order: wsW[mat][ct(16)][kb(8)][lane(64)][j(8)]
__global__ void setup_kernel(const float* __restrict__ Wq, const float* __restrict__ Wk,
                             const float* __restrict__ Wv, const float* __restrict__ lw,
                             unsigned short* __restrict__ wsW) {
    int tid = blockIdx.x * blockDim.x + threadIdx.x;   // 65536 threads
    int ct = tid >> 12, kb = (tid >> 9) & 7, l = (tid >> 3) & 63, j = tid & 7;
    int col = ct * 16 + (l & 15);
    int k   = kb * 32 + (l >> 4) * 8 + j;
    wsW[tid]          = f2bf(Wq[k * 256 + col]);   // B[k][col] of Wq
    wsW[65536 + tid]  = f2bf(Wk[k * 256 + col]);
    wsW[131072 + tid] = f2bf(Wv[k * 256 + col]);
    wsW[196608 + tid] = f2bf(lw[col * 256 + k]);   // B[k][col] of lin_w^T
}

// acc[4][2] += A(lds [32][256]) @ W(global bf16, fragment order); wave w: cols w*64..+63
// Depth-4 rolling B-prefetch, FORCED via asm volatile (cannot be sunk like r6/r8/r10,
// cannot spill like r9's depth-8: 64 frag VGPRs fits the 170 cap). Counted vmcnt:
// waits are store-prefix-independent (FIFO completion).
__device__ __forceinline__ void gemm32x256(const unsigned short* A,
                                           const unsigned short* __restrict__ W,
                                           int w, int l, fl4 acc[4][2]) {
    const int qd = l >> 4, c16 = l & 15;
    const unsigned short* Wb = W + w * 16384 + l * 8;   // (w*4 colTiles)*4096
    sh8 bfr[4][4];
#pragma unroll
    for (int kb = 0; kb < 3; ++kb)                 // prologue: 12 loads in flight
#pragma unroll
        for (int ci = 0; ci < 4; ++ci)
            asm volatile("global_load_dwordx4 %0, %1, off"
                         : "=v"(bfr[kb][ci]) : "v"(Wb + ci * 4096 + kb * 512));
    sh8 afr[2][2];
#pragma unroll
    for (int rt = 0; rt < 2; ++rt)
        afr[0][rt] = *(const sh8*)(A + EA(rt * 16 + c16, qd * 8));
#pragma unroll
    for (int kb = 0; kb < 8; ++kb) {
        const int cur = kb & 3, nxt = (kb + 3) & 3, ab = kb & 1;  // static (unrolled)
        if (kb < 5)                                // rolling issue: kb+3
#pragma unroll
            for (int ci = 0; ci < 4; ++ci)
                asm volatile("global_load_dwordx4 %0, %1, off"
                             : "=v"(bfr[nxt][ci]) : "v"(Wb + ci * 4096 + (kb + 3) * 512));
        if (kb < 7)
#pragma unroll
            for (int rt = 0; rt < 2; ++rt)
                afr[ab ^ 1][rt] = *(const sh8*)(A + EA(rt * 16 + c16, (kb + 1) * 32 + qd * 8));
        // need first 4*(kb+1) loads done; issued = 12 + 4*min(kb+1,5)
        if      (kb < 5)  vmwait<12>();
        else if (kb == 5) vmwait<8>();
        else if (kb == 6) vmwait<4>();
        else              vmwait<0>();
#pragma unroll
        for (int ci = 0; ci < 4; ++ci)
#pragma unroll
            for (int rt = 0; rt < 2; ++rt)
                acc[ci][rt] = __builtin_amdgcn_mfma_f32_16x16x32_bf16(
                    afr[ab][rt], bfr[cur][ci], acc[ci][rt], 0, 0, 0);
    }
}

__launch_bounds__(256, 3)
__global__ void fused_kernel(const float* __restrict__ inputs, const float* __restrict__ EC,
                             const float* __restrict__ pos_emb, const float* __restrict__ lin_b,
                             const unsigned short* __restrict__ wsW,
                             float* __restrict__ d_out) {
    extern __shared__ char smem[];
    unsigned short* X = (unsigned short*)smem;   // temporal -> v_T      [32][256] / [256][32]
    unsigned short* Y = X + 8192;                // EC -> k -> P(ST lay) [32][256]
    unsigned short* Z = Y + 8192;                // q -> ctx             [32][256]
    float*       outL = (float*)(Z + 8192);      // [2][256] f32

    const int tid = threadIdx.x;
    const int w = tid >> 6, l = tid & 63;
    const int qd = l >> 4, c16 = l & 15;
    const size_t rbase = (size_t)blockIdx.x * 32;
    const int n0 = blockIdx.x * 2;

    // ---- stage: issue ALL global loads first (one HBM round-trip), then convert ----
    fl4 ins[8], ecs[8], pes[8];
#pragma unroll
    for (int i = 0; i < 8; ++i) {
        size_t g = (rbase + i * 4 + w) * 256 + 4 * l;
        ins[i] = *(const fl4*)(inputs + g);
        ecs[i] = *(const fl4*)(EC + g);
    }
#pragma unroll
    for (int i = 0; i < 8; ++i)
        pes[i] = *(const fl4*)(pos_emb + ((i * 4 + w) & 15) * 256 + 4 * l);

    // zero outL (tmean/ctx-mean accumulate via LDS atomics after B1)
    outL[tid] = 0.f;
    outL[256 + tid] = 0.f;

    fl4 tacc0 = {0.f, 0.f, 0.f, 0.f}, tacc1 = {0.f, 0.f, 0.f, 0.f};
#pragma unroll
    for (int i = 0; i < 8; ++i) {
        int row = i * 4 + w;
        fl4 t4 = ins[i] + pes[i];
        if (i < 4) tacc0 += t4; else tacc1 += t4;
        *(uint2*)(X + EA(row, 4 * l)) = make_uint2(cvt2u(t4[0], t4[1]), cvt2u(t4[2], t4[3]));
        *(uint2*)(Y + EA(row, 4 * l)) =
            make_uint2(cvt2u(ecs[i][0], ecs[i][1]), cvt2u(ecs[i][2], ecs[i][3]));
    }
    __syncthreads();                               // B1

    // tmean contribution (rows w,4+w,8+w,12+w -> node0; +16 -> node1)
#pragma unroll
    for (int j = 0; j < 4; ++j) {
        atomicAdd(&outL[4 * l + j], tacc0[j] * 0.0625f);
        atomicAdd(&outL[256 + 4 * l + j], tacc1[j] * 0.0625f);
    }

    // ---- k = EC@Wk (in-place to Y), q = temporal@Wq (to Z) ----
    {
        fl4 aK[4][2] = {}, aQ[4][2] = {};
        gemm32x256(Y, wsW + 65536, w, l, aK);
        gemm32x256(X, wsW, w, l, aQ);
        __syncthreads();                           // B2: all X/Y reads done
#pragma unroll
        for (int ci = 0; ci < 4; ++ci) {
            int col = w * 64 + ci * 16 + c16;
#pragma unroll
            for (int rt = 0; rt < 2; ++rt) {
                int r0 = rt * 16 + qd * 4;
                unsigned int k01 = cvt2u(aK[ci][rt][0], aK[ci][rt][1]);
                unsigned int k23 = cvt2u(aK[ci][rt][2], aK[ci][rt][3]);
                unsigned int q01 = cvt2u(aQ[ci][rt][0], aQ[ci][rt][1]);
                unsigned int q23 = cvt2u(aQ[ci][rt][2], aQ[ci][rt][3]);
                Y[EA(r0 + 0, col)] = (unsigned short)k01;
                Y[EA(r0 + 1, col)] = (unsigned short)(k01 >> 16);
                Y[EA(r0 + 2, col)] = (unsigned short)k23;
                Y[EA(r0 + 3, col)] = (unsigned short)(k23 >> 16);
                Z[EA(r0 + 0, col)] = (unsigned short)q01;
                Z[EA(r0 + 1, col)] = (unsigned short)(q01 >> 16);
                Z[EA(r0 + 2, col)] = (unsigned short)q23;
                Z[EA(r0 + 3, col)] = (unsigned short)(q23 >> 16);
            }
        }
    }
    __syncthreads();                               // B3: k,q ready

    // ---- QK^T transposed: st[h] = K @ Q^T -> lane holds S[qt=c16][kt=qd*4+i2] ----
    const int nd = w >> 1, hb = (w & 1) * 8;
    fl4 st[8];
#pragma unroll
    for (int h = 0; h < 8; ++h) {
        sh8 ka = {}, qa = {};
        if (l < 32) {                              // d-dim K=16 padded to 32
            ka = *(const sh8*)(Y + EA(nd * 16 + c16, (hb + h) * 16 + qd * 8));
            qa = *(const sh8*)(Z + EA(nd * 16 + c16, (hb + h) * 16 + qd * 8));
        }
        fl4 z = {};
        st[h] = __builtin_amdgcn_mfma_f32_16x16x32_bf16(ka, qa, z, 0, 0, 0);
    }

    // ---- v = temporal@Wv (overlaps softmax below) ----
    fl4 aV[4][2] = {};
    gemm32x256(X, wsW + 131072, w, l, aV);

    // ---- softmax over kt: 3 in-lane adds + 2 shfl; no max-subtract (f32 exp headroom) ----
#pragma unroll
    for (int h = 0; h < 8; ++h) {
        fl4 e;
#pragma unroll
        for (int i2 = 0; i2 < 4; ++i2)
            e[i2] = __builtin_amdgcn_exp2f(st[h][i2] * 0.36067376022f);  // exp(s*0.25)
        float sum = e[0] + e[1] + e[2] + e[3];
        sum += __shfl_xor(sum, 16);
        sum += __shfl_xor(sum, 32);
        float r = __builtin_amdgcn_rcpf(sum);
        // P in ST layout: row = node*16+qt, cols h*16 + qd*4 + i2 (contiguous 4)
        *(uint2*)(Y + EA(nd * 16 + c16, (hb + h) * 16 + qd * 4)) =
            make_uint2(cvt2u(e[0] * r, e[1] * r), cvt2u(e[2] * r, e[3] * r));
    }
    __syncthreads();                               // B4: X reads (v GEMM) done, P written

    // ---- v_T -> X (t contiguous per i2 -> uint2 stores) ----
#pragma unroll
    for (int ci = 0; ci < 4; ++ci) {
        int col = w * 64 + ci * 16 + c16;
#pragma unroll
        for (int rt = 0; rt < 2; ++rt) {
            int t0 = rt * 16 + qd * 4;
            *(uint2*)(X + EV(col, t0)) =
                make_uint2(cvt2u(aV[ci][rt][0], aV[ci][rt][1]),
                           cvt2u(aV[ci][rt][2], aV[ci][rt][3]));
        }
    }
    __syncthreads();                               // B5: P, v_T ready

    // ---- PV: ctx -> Z (q dead); fold ctx-mean into outL ----
#pragma unroll
    for (int h = 0; h < 8; ++h) {
        sh8 pa = {};
        if (l < 32)                                // kt 16..31 pad = zero
            pa = *(const sh8*)(Y + EA(nd * 16 + c16, (hb + h) * 16 + qd * 8));
        sh8 vb = *(const sh8*)(X + EV((hb + h) * 16 + c16, nd * 16 + (qd & 1) * 8));
        fl4 z = {};
        fl4 cx = __builtin_amdgcn_mfma_f32_16x16x32_bf16(pa, vb, z, 0, 0, 0);
        int col = (hb + h) * 16 + c16;
        unsigned int c01 = cvt2u(cx[0], cx[1]);
        unsigned int c23 = cvt2u(cx[2], cx[3]);
        int r0 = nd * 16 + qd * 4;
        Z[EA(r0 + 0, col)] = (unsigned short)c01;
        Z[EA(r0 + 1, col)] = (unsigned short)(c01 >> 16);
        Z[EA(r0 + 2, col)] = (unsigned short)c23;
        Z[EA(r0 + 3, col)] = (unsigned short)(c23 >> 16);
        atomicAdd(&outL[nd * 256 + col], (cx[0] + cx[1] + cx[2] + cx[3]) * 0.0625f);
    }

    // ---- ST dump: Y is [node][qt][h*16+kt] => coalesced fl4 stores ----
#pragma unroll
    for (int ch = 0; ch < 8; ++ch) {
        int flat = ch * 1024 + tid * 4;
        int row = flat >> 8, col = flat & 255;
        sh4 pv = *(const sh4*)(Y + (row << 8) + (col ^ ((row & 7) << 3)));
        fl4 o;
#pragma unroll
        for (int j = 0; j < 4; ++j) o[j] = bf2f((unsigned short)pv[j]);
        *(fl4*)(d_out + OUT0 + (size_t)blockIdx.x * 8192 + flat) = o;
    }
    __syncthreads();                               // B6: ctx(Z) ready

    // ---- ff = relu(ctx@lin_w^T + b); mean over T into outL (ctx-mean already added) ----
    {
        fl4 aF[4][2] = {};
        gemm32x256(Z, wsW + 196608, w, l, aF);
#pragma unroll
        for (int ci = 0; ci < 4; ++ci) {
            int col = w * 64 + ci * 16 + c16;
            float bias = lin_b[col];
#pragma unroll
            for (int rt = 0; rt < 2; ++rt) {
                float ssum = 0.f;
#pragma unroll
                for (int i2 = 0; i2 < 4; ++i2)
                    ssum += fmaxf(aF[ci][rt][i2] + bias, 0.f);
                ssum += __shfl_xor(ssum, 16);      // sum 4 qd row-groups -> all 16 t
                ssum += __shfl_xor(ssum, 32);
                if (l < 16) outL[rt * 256 + col] += ssum * 0.0625f;
            }
        }
    }
    __syncthreads();                               // B7

    // ---- write out[n][c] ----
    if (tid < 128) {
        int idx = tid * 4;
        fl4 o = *(const fl4*)(outL + idx);
        *(fl4*)(d_out + (size_t)n0 * 256 + idx) = o;
    }
}

extern "C" void kernel_launch(void* const* d_in, const int* in_sizes, int n_in,
                              void* d_out, int out_size, void* d_ws, size_t ws_size,
                              hipStream_t stream) {
    const float* inputs = (const float*)d_in[0];
    const float* EC     = (const float*)d_in[1];
    const float* pos    = (const float*)d_in[2];
    const float* Wq     = (const float*)d_in[3];
    const float* Wk     = (const float*)d_in[4];
    const float* Wv     = (const float*)d_in[5];
    const float* lw     = (const float*)d_in[6];
    const float* lb     = (const float*)d_in[7];
    unsigned short* wsW = (unsigned short*)d_ws;   // 4 x 65536 bf16 = 512 KB
    float* out = (float*)d_out;

    (void)hipFuncSetAttribute(reinterpret_cast<const void*>(fused_kernel),
                              hipFuncAttributeMaxDynamicSharedMemorySize, 51200);

    setup_kernel<<<256, 256, 0, stream>>>(Wq, Wk, Wv, lw, wsW);
    fused_kernel<<<16384, 256, 51200, stream>>>(inputs, EC, pos, lb, wsW, out);
}

// Round 13
// 650.832 us; speedup vs baseline: 1.4133x; 1.0192x over previous
//
#include <hip/hip_runtime.h>

#define OUT0 8388608   // N*F floats: start of ST region in d_out

typedef __attribute__((ext_vector_type(8))) short sh8;
typedef __attribute__((ext_vector_type(4))) short sh4;
typedef __attribute__((ext_vector_type(4))) float fl4;

__device__ __forceinline__ unsigned short f2bf(float f) {
    unsigned int u = __builtin_bit_cast(unsigned int, f);
    u += 0x7FFFu + ((u >> 16) & 1u);               // round-to-nearest-even
    return (unsigned short)(u >> 16);
}
__device__ __forceinline__ unsigned int cvt2u(float a, float b) {
    return (unsigned int)f2bf(a) | ((unsigned int)f2bf(b) << 16);
}
__device__ __forceinline__ float bf2f(unsigned short s) {
    unsigned int u = ((unsigned int)s) << 16;
    return __builtin_bit_cast(float, u);
}

template<int N>
__device__ __forceinline__ void vmwait() {
    asm volatile("s_waitcnt vmcnt(%0)" :: "n"(N) : "memory");
    __builtin_amdgcn_sched_barrier(0);             // rule #18: MFMAs must not hoist above
}

// SGPR-based B-fragment load: wave-uniform SGPR base + per-lane 32-bit voffset +
// 13-bit imm. Zero per-load VALU (vs 2 VALU ops to materialize each 64-bit address).
template<int IMM>
__device__ __forceinline__ void gls(sh8 &dst, unsigned voff, unsigned long long base) {
    asm volatile("global_load_dwordx4 %0, %1, %2 offset:%3"
                 : "=v"(dst) : "v"(voff), "s"(base), "n"(IMM));
}
__device__ __forceinline__ unsigned long long rfl64(const void* p) {
    unsigned long long u = (unsigned long long)p;     // wave-uniform by construction
    unsigned lo = (unsigned)__builtin_amdgcn_readfirstlane((int)(unsigned)u);
    unsigned hi = (unsigned)__builtin_amdgcn_readfirstlane((int)(unsigned)(u >> 32));
    return ((unsigned long long)hi << 32) | lo;
}

// [32 rows][256 cols] bf16 tile, XOR-swizzled for conflict-free ds_read_b128
#define EA(r,c) (((r)<<8) + ((c) ^ (((r)&7)<<3)))
// v_T tile [256 chan][32 rows]
#define EV(c,r) (((c)<<5) + ((r) ^ (((c)&3)<<3)))

// W pre-swizzled to MFMA-fragment order: wsW[mat][ct(16)][kb(8)][lane(64)][j(8)]
__global__ void setup_kernel(const float* __restrict__ Wq, const float* __restrict__ Wk,
                             const float* __restrict__ Wv, const float* __restrict__ lw,
                             unsigned short* __restrict__ wsW) {
    int tid = blockIdx.x * blockDim.x + threadIdx.x;   // 65536 threads
    int ct = tid >> 12, kb = (tid >> 9) & 7, l = (tid >> 3) & 63, j = tid & 7;
    int col = ct * 16 + (l & 15);
    int k   = kb * 32 + (l >> 4) * 8 + j;
    wsW[tid]          = f2bf(Wq[k * 256 + col]);   // B[k][col] of Wq
    wsW[65536 + tid]  = f2bf(Wk[k * 256 + col]);
    wsW[131072 + tid] = f2bf(Wv[k * 256 + col]);
    wsW[196608 + tid] = f2bf(lw[col * 256 + k]);   // B[k][col] of lin_w^T
}

// One K-step of the depth-4 rolling-prefetch GEMM (r11 schedule, SGPR addressing).
// bs[ci*2 + half]: SGPR base = Wb + ci*8192B + half*4096B; imm = (kbt&3)*1024B.
template<int KB>
__device__ __forceinline__ void gstep(const unsigned short* A, int qd, int c16,
                                      unsigned voff, const unsigned long long* bs,
                                      sh8 bfr[4][4], sh8 afr[2][2], fl4 acc[4][2]) {
    constexpr int cur = KB & 3, ab = KB & 1;
    if constexpr (KB < 5) {                        // rolling issue: kb+3
        constexpr int kbt = KB + 3, nxt = kbt & 3, half = kbt >> 2, imm = (kbt & 3) * 1024;
        gls<imm>(bfr[nxt][0], voff, bs[0 + half]);
        gls<imm>(bfr[nxt][1], voff, bs[2 + half]);
        gls<imm>(bfr[nxt][2], voff, bs[4 + half]);
        gls<imm>(bfr[nxt][3], voff, bs[6 + half]);
    }
    if constexpr (KB < 7) {
#pragma unroll
        for (int rt = 0; rt < 2; ++rt)
            afr[ab ^ 1][rt] = *(const sh8*)(A + EA(rt * 16 + c16, (KB + 1) * 32 + qd * 8));
    }
    if constexpr      (KB < 5)  vmwait<12>();
    else if constexpr (KB == 5) vmwait<8>();
    else if constexpr (KB == 6) vmwait<4>();
    else                        vmwait<0>();
#pragma unroll
    for (int ci = 0; ci < 4; ++ci)
#pragma unroll
        for (int rt = 0; rt < 2; ++rt)
            acc[ci][rt] = __builtin_amdgcn_mfma_f32_16x16x32_bf16(
                afr[ab][rt], bfr[cur][ci], acc[ci][rt], 0, 0, 0);
}

// acc[4][2] += A(lds [32][256]) @ W(global bf16, fragment order); wave w: cols w*64..+63
__device__ __forceinline__ void gemm32x256(const unsigned short* A,
                                           const unsigned short* __restrict__ W,
                                           int w, int l, fl4 acc[4][2]) {
    const int qd = l >> 4, c16 = l & 15;
    const unsigned voff = (unsigned)(l * 16);      // per-lane byte offset
    unsigned long long wb = rfl64(W + w * 16384);  // wave-uniform -> SGPR
    unsigned long long bs[8];
#pragma unroll
    for (int ci = 0; ci < 4; ++ci) {
        bs[ci * 2]     = wb + (unsigned)(ci * 8192);
        bs[ci * 2 + 1] = wb + (unsigned)(ci * 8192 + 4096);
    }
    sh8 bfr[4][4], afr[2][2];
    // prologue: pairs 0..2 (12 loads in flight), all half=0
    gls<0>(bfr[0][0], voff, bs[0]); gls<0>(bfr[0][1], voff, bs[2]);
    gls<0>(bfr[0][2], voff, bs[4]); gls<0>(bfr[0][3], voff, bs[6]);
    gls<1024>(bfr[1][0], voff, bs[0]); gls<1024>(bfr[1][1], voff, bs[2]);
    gls<1024>(bfr[1][2], voff, bs[4]); gls<1024>(bfr[1][3], voff, bs[6]);
    gls<2048>(bfr[2][0], voff, bs[0]); gls<2048>(bfr[2][1], voff, bs[2]);
    gls<2048>(bfr[2][2], voff, bs[4]); gls<2048>(bfr[2][3], voff, bs[6]);
#pragma unroll
    for (int rt = 0; rt < 2; ++rt)
        afr[0][rt] = *(const sh8*)(A + EA(rt * 16 + c16, qd * 8));
    gstep<0>(A, qd, c16, voff, bs, bfr, afr, acc);
    gstep<1>(A, qd, c16, voff, bs, bfr, afr, acc);
    gstep<2>(A, qd, c16, voff, bs, bfr, afr, acc);
    gstep<3>(A, qd, c16, voff, bs, bfr, afr, acc);
    gstep<4>(A, qd, c16, voff, bs, bfr, afr, acc);
    gstep<5>(A, qd, c16, voff, bs, bfr, afr, acc);
    gstep<6>(A, qd, c16, voff, bs, bfr, afr, acc);
    gstep<7>(A, qd, c16, voff, bs, bfr, afr, acc);
}

__launch_bounds__(256, 3)
__global__ void fused_kernel(const float* __restrict__ inputs, const float* __restrict__ EC,
                             const float* __restrict__ pos_emb, const float* __restrict__ lin_b,
                             const unsigned short* __restrict__ wsW,
                             float* __restrict__ d_out) {
    extern __shared__ char smem[];
    unsigned short* X = (unsigned short*)smem;   // temporal -> v_T      [32][256] / [256][32]
    unsigned short* Y = X + 8192;                // EC -> k -> P(ST lay) [32][256]
    unsigned short* Z = Y + 8192;                // q -> ctx             [32][256]
    float*       outL = (float*)(Z + 8192);      // [2][256] f32

    const int tid = threadIdx.x;
    const int w = tid >> 6, l = tid & 63;
    const int qd = l >> 4, c16 = l & 15;
    const size_t rbase = (size_t)blockIdx.x * 32;
    const int n0 = blockIdx.x * 2;

    // ---- stage: issue ALL global loads first (one HBM round-trip), then convert ----
    fl4 ins[8], ecs[8], pes[8];
#pragma unroll
    for (int i = 0; i < 8; ++i) {
        size_t g = (rbase + i * 4 + w) * 256 + 4 * l;
        ins[i] = *(const fl4*)(inputs + g);
        ecs[i] = *(const fl4*)(EC + g);
    }
#pragma unroll
    for (int i = 0; i < 8; ++i)
        pes[i] = *(const fl4*)(pos_emb + ((i * 4 + w) & 15) * 256 + 4 * l);

    // zero outL (tmean/ctx-mean accumulate via LDS atomics after B1)
    outL[tid] = 0.f;
    outL[256 + tid] = 0.f;

    fl4 tacc0 = {0.f, 0.f, 0.f, 0.f}, tacc1 = {0.f, 0.f, 0.f, 0.f};
#pragma unroll
    for (int i = 0; i < 8; ++i) {
        int row = i * 4 + w;
        fl4 t4 = ins[i] + pes[i];
        if (i < 4) tacc0 += t4; else tacc1 += t4;
        *(uint2*)(X + EA(row, 4 * l)) = make_uint2(cvt2u(t4[0], t4[1]), cvt2u(t4[2], t4[3]));
        *(uint2*)(Y + EA(row, 4 * l)) =
            make_uint2(cvt2u(ecs[i][0], ecs[i][1]), cvt2u(ecs[i][2], ecs[i][3]));
    }
    __syncthreads();                               // B1

    // tmean contribution (rows w,4+w,8+w,12+w -> node0; +16 -> node1)
#pragma unroll
    for (int j = 0; j < 4; ++j) {
        atomicAdd(&outL[4 * l + j], tacc0[j] * 0.0625f);
        atomicAdd(&outL[256 + 4 * l + j], tacc1[j] * 0.0625f);
    }

    // ---- k = EC@Wk (in-place to Y), q = temporal@Wq (to Z) ----
    {
        fl4 aK[4][2] = {}, aQ[4][2] = {};
        gemm32x256(Y, wsW + 65536, w, l, aK);
        gemm32x256(X, wsW, w, l, aQ);
        __syncthreads();                           // B2: all X/Y reads done
#pragma unroll
        for (int ci = 0; ci < 4; ++ci) {
            int col = w * 64 + ci * 16 + c16;
#pragma unroll
            for (int rt = 0; rt < 2; ++rt) {
                int r0 = rt * 16 + qd * 4;
                unsigned int k01 = cvt2u(aK[ci][rt][0], aK[ci][rt][1]);
                unsigned int k23 = cvt2u(aK[ci][rt][2], aK[ci][rt][3]);
                unsigned int q01 = cvt2u(aQ[ci][rt][0], aQ[ci][rt][1]);
                unsigned int q23 = cvt2u(aQ[ci][rt][2], aQ[ci][rt][3]);
                Y[EA(r0 + 0, col)] = (unsigned short)k01;
                Y[EA(r0 + 1, col)] = (unsigned short)(k01 >> 16);
                Y[EA(r0 + 2, col)] = (unsigned short)k23;
                Y[EA(r0 + 3, col)] = (unsigned short)(k23 >> 16);
                Z[EA(r0 + 0, col)] = (unsigned short)q01;
                Z[EA(r0 + 1, col)] = (unsigned short)(q01 >> 16);
                Z[EA(r0 + 2, col)] = (unsigned short)q23;
                Z[EA(r0 + 3, col)] = (unsigned short)(q23 >> 16);
            }
        }
    }
    __syncthreads();                               // B3: k,q ready

    // ---- QK^T transposed: st[h] = K @ Q^T -> lane holds S[qt=c16][kt=qd*4+i2] ----
    const int nd = w >> 1, hb = (w & 1) * 8;
    fl4 st[8];
#pragma unroll
    for (int h = 0; h < 8; ++h) {
        sh8 ka = {}, qa = {};
        if (l < 32) {                              // d-dim K=16 padded to 32
            ka = *(const sh8*)(Y + EA(nd * 16 + c16, (hb + h) * 16 + qd * 8));
            qa = *(const sh8*)(Z + EA(nd * 16 + c16, (hb + h) * 16 + qd * 8));
        }
        fl4 z = {};
        st[h] = __builtin_amdgcn_mfma_f32_16x16x32_bf16(ka, qa, z, 0, 0, 0);
    }

    // ---- v = temporal@Wv (overlaps softmax below) ----
    fl4 aV[4][2] = {};
    gemm32x256(X, wsW + 131072, w, l, aV);

    // ---- softmax over kt: 3 in-lane adds + 2 shfl; no max-subtract (f32 exp headroom) ----
#pragma unroll
    for (int h = 0; h < 8; ++h) {
        fl4 e;
#pragma unroll
        for (int i2 = 0; i2 < 4; ++i2)
            e[i2] = __builtin_amdgcn_exp2f(st[h][i2] * 0.36067376022f);  // exp(s*0.25)
        float sum = e[0] + e[1] + e[2] + e[3];
        sum += __shfl_xor(sum, 16);
        sum += __shfl_xor(sum, 32);
        float r = __builtin_amdgcn_rcpf(sum);
        // P in ST layout: row = node*16+qt, cols h*16 + qd*4 + i2 (contiguous 4)
        *(uint2*)(Y + EA(nd * 16 + c16, (hb + h) * 16 + qd * 4)) =
            make_uint2(cvt2u(e[0] * r, e[1] * r), cvt2u(e[2] * r, e[3] * r));
    }
    __syncthreads();                               // B4: X reads (v GEMM) done, P written

    // ---- v_T -> X (t contiguous per i2 -> uint2 stores) ----
#pragma unroll
    for (int ci = 0; ci < 4; ++ci) {
        int col = w * 64 + ci * 16 + c16;
#pragma unroll
        for (int rt = 0; rt < 2; ++rt) {
            int t0 = rt * 16 + qd * 4;
            *(uint2*)(X + EV(col, t0)) =
                make_uint2(cvt2u(aV[ci][rt][0], aV[ci][rt][1]),
                           cvt2u(aV[ci][rt][2], aV[ci][rt][3]));
        }
    }
    __syncthreads();                               // B5: P, v_T ready

    // ---- PV: ctx -> Z (q dead); fold ctx-mean into outL ----
#pragma unroll
    for (int h = 0; h < 8; ++h) {
        sh8 pa = {};
        if (l < 32)                                // kt 16..31 pad = zero
            pa = *(const sh8*)(Y + EA(nd * 16 + c16, (hb + h) * 16 + qd * 8));
        sh8 vb = *(const sh8*)(X + EV((hb + h) * 16 + c16, nd * 16 + (qd & 1) * 8));
        fl4 z = {};
        fl4 cx = __builtin_amdgcn_mfma_f32_16x16x32_bf16(pa, vb, z, 0, 0, 0);
        int col = (hb + h) * 16 + c16;
        unsigned int c01 = cvt2u(cx[0], cx[1]);
        unsigned int c23 = cvt2u(cx[2], cx[3]);
        int r0 = nd * 16 + qd * 4;
        Z[EA(r0 + 0, col)] = (unsigned short)c01;
        Z[EA(r0 + 1, col)] = (unsigned short)(c01 >> 16);
        Z[EA(r0 + 2, col)] = (unsigned short)c23;
        Z[EA(r0 + 3, col)] = (unsigned short)(c23 >> 16);
        atomicAdd(&outL[nd * 256 + col], (cx[0] + cx[1] + cx[2] + cx[3]) * 0.0625f);
    }

    // ---- ST dump: Y is [node][qt][h*16+kt] => coalesced fl4 stores ----
#pragma unroll
    for (int ch = 0; ch < 8; ++ch) {
        int flat = ch * 1024 + tid * 4;
        int row = flat >> 8, col = flat & 255;
        sh4 pv = *(const sh4*)(Y + (row << 8) + (col ^ ((row & 7) << 3)));
        fl4 o;
#pragma unroll
        for (int j = 0; j < 4; ++j) o[j] = bf2f((unsigned short)pv[j]);
        *(fl4*)(d_out + OUT0 + (size_t)blockIdx.x * 8192 + flat) = o;
    }
    __syncthreads();                               // B6: ctx(Z) ready

    // ---- ff = relu(ctx@lin_w^T + b); mean over T into outL (ctx-mean already added) ----
    {
        fl4 aF[4][2] = {};
        gemm32x256(Z, wsW + 196608, w, l, aF);
#pragma unroll
        for (int ci = 0; ci < 4; ++ci) {
            int col = w * 64 + ci * 16 + c16;
            float bias = lin_b[col];
#pragma unroll
            for (int rt = 0; rt < 2; ++rt) {
                float ssum = 0.f;
#pragma unroll
                for (int i2 = 0; i2 < 4; ++i2)
                    ssum += fmaxf(aF[ci][rt][i2] + bias, 0.f);
                ssum += __shfl_xor(ssum, 16);      // sum 4 qd row-groups -> all 16 t
                ssum += __shfl_xor(ssum, 32);
                if (l < 16) outL[rt * 256 + col] += ssum * 0.0625f;
            }
        }
    }
    __syncthreads();                               // B7

    // ---- write out[n][c] ----
    if (tid < 128) {
        int idx = tid * 4;
        fl4 o = *(const fl4*)(outL + idx);
        *(fl4*)(d_out + (size_t)n0 * 256 + idx) = o;
    }
}

extern "C" void kernel_launch(void* const* d_in, const int* in_sizes, int n_in,
                              void* d_out, int out_size, void* d_ws, size_t ws_size,
                              hipStream_t stream) {
    const float* inputs = (const float*)d_in[0];
    const float* EC     = (const float*)d_in[1];
    const float* pos    = (const float*)d_in[2];
    const float* Wq     = (const float*)d_in[3];
    const float* Wk     = (const float*)d_in[4];
    const float* Wv     = (const float*)d_in[5];
    const float* lw     = (const float*)d_in[6];
    const float* lb     = (const float*)d_in[7];
    unsigned short* wsW = (unsigned short*)d_ws;   // 4 x 65536 bf16 = 512 KB
    float* out = (float*)d_out;

    (void)hipFuncSetAttribute(reinterpret_cast<const void*>(fused_kernel),
                              hipFuncAttributeMaxDynamicSharedMemorySize, 51200);

    setup_kernel<<<256, 256, 0, stream>>>(Wq, Wk, Wv, lw, wsW);
    fused_kernel<<<16384, 256, 51200, stream>>>(inputs, EC, pos, lb, wsW, out);
}

// Round 15
// 593.169 us; speedup vs baseline: 1.5507x; 1.0972x over previous
//
#include <hip/hip_runtime.h>
#include <hip/hip_bf16.h>

#define OUT0 8388608   // N*F floats: start of ST region in d_out

typedef __attribute__((ext_vector_type(8))) short sh8;
typedef __attribute__((ext_vector_type(4))) short sh4;
typedef __attribute__((ext_vector_type(4))) float fl4;

__device__ __forceinline__ unsigned short f2bf(float f) {
    unsigned int u = __builtin_bit_cast(unsigned int, f);
    u += 0x7FFFu + ((u >> 16) & 1u);               // round-to-nearest-even
    return (unsigned short)(u >> 16);
}
// Packed f32x2 -> bf16x2 via the documented HIP API (compiler emits the packed
// HW cvt on gfx950 — m240: "compiler handles it"; hand-asm cvt_pk NaN'd in r14).
__device__ __forceinline__ unsigned int cvt2u(float a, float b) {
    __hip_bfloat162 h = __float22bfloat162_rn(make_float2(a, b));  // lo=a, hi=b
    unsigned int r;
    __builtin_memcpy(&r, &h, sizeof(r));
    return r;
}
__device__ __forceinline__ float bf2f(unsigned short s) {
    unsigned int u = ((unsigned int)s) << 16;
    return __builtin_bit_cast(float, u);
}

template<int N>
__device__ __forceinline__ void vmwait() {
    asm volatile("s_waitcnt vmcnt(%0)" :: "n"(N) : "memory");
    __builtin_amdgcn_sched_barrier(0);             // rule #18: MFMAs must not hoist above
}

// SGPR-based B-fragment load: wave-uniform SGPR base + per-lane 32-bit voffset +
// 13-bit imm. Zero per-load VALU.
template<int IMM>
__device__ __forceinline__ void gls(sh8 &dst, unsigned voff, unsigned long long base) {
    asm volatile("global_load_dwordx4 %0, %1, %2 offset:%3"
                 : "=v"(dst) : "v"(voff), "s"(base), "n"(IMM));
}
__device__ __forceinline__ unsigned long long rfl64(const void* p) {
    unsigned long long u = (unsigned long long)p;     // wave-uniform by construction
    unsigned lo = (unsigned)__builtin_amdgcn_readfirstlane((int)(unsigned)u);
    unsigned hi = (unsigned)__builtin_amdgcn_readfirstlane((int)(unsigned)(u >> 32));
    return ((unsigned long long)hi << 32) | lo;
}

// [32 rows][256 cols] bf16 tile, XOR-swizzled for conflict-free ds_read_b128
#define EA(r,c) (((r)<<8) + ((c) ^ (((r)&7)<<3)))
// v_T tile [256 chan][32 rows]
#define EV(c,r) (((c)<<5) + ((r) ^ (((c)&3)<<3)))

// W pre-swizzled to MFMA-fragment order: wsW[mat][ct(16)][kb(8)][lane(64)][j(8)]
__global__ void setup_kernel(const float* __restrict__ Wq, const float* __restrict__ Wk,
                             const float* __restrict__ Wv, const float* __restrict__ lw,
                             unsigned short* __restrict__ wsW) {
    int tid = blockIdx.x * blockDim.x + threadIdx.x;   // 65536 threads
    int ct = tid >> 12, kb = (tid >> 9) & 7, l = (tid >> 3) & 63, j = tid & 7;
    int col = ct * 16 + (l & 15);
    int k   = kb * 32 + (l >> 4) * 8 + j;
    wsW[tid]          = f2bf(Wq[k * 256 + col]);   // B[k][col] of Wq
    wsW[65536 + tid]  = f2bf(Wk[k * 256 + col]);
    wsW[131072 + tid] = f2bf(Wv[k * 256 + col]);
    wsW[196608 + tid] = f2bf(lw[col * 256 + k]);   // B[k][col] of lin_w^T
}

// One K-step of the depth-4 rolling-prefetch GEMM (r11 schedule, SGPR addressing).
template<int KB>
__device__ __forceinline__ void gstep(const unsigned short* A, int qd, int c16,
                                      unsigned voff, const unsigned long long* bs,
                                      sh8 bfr[4][4], sh8 afr[2][2], fl4 acc[4][2]) {
    constexpr int cur = KB & 3, ab = KB & 1;
    if constexpr (KB < 5) {                        // rolling issue: kb+3
        constexpr int kbt = KB + 3, nxt = kbt & 3, half = kbt >> 2, imm = (kbt & 3) * 1024;
        gls<imm>(bfr[nxt][0], voff, bs[0 + half]);
        gls<imm>(bfr[nxt][1], voff, bs[2 + half]);
        gls<imm>(bfr[nxt][2], voff, bs[4 + half]);
        gls<imm>(bfr[nxt][3], voff, bs[6 + half]);
    }
    if constexpr (KB < 7) {
#pragma unroll
        for (int rt = 0; rt < 2; ++rt)
            afr[ab ^ 1][rt] = *(const sh8*)(A + EA(rt * 16 + c16, (KB + 1) * 32 + qd * 8));
    }
    if constexpr      (KB < 5)  vmwait<12>();
    else if constexpr (KB == 5) vmwait<8>();
    else if constexpr (KB == 6) vmwait<4>();
    else                        vmwait<0>();
#pragma unroll
    for (int ci = 0; ci < 4; ++ci)
#pragma unroll
        for (int rt = 0; rt < 2; ++rt)
            acc[ci][rt] = __builtin_amdgcn_mfma_f32_16x16x32_bf16(
                afr[ab][rt], bfr[cur][ci], acc[ci][rt], 0, 0, 0);
}

// acc[4][2] += A(lds [32][256]) @ W(global bf16, fragment order); wave w: cols w*64..+63
__device__ __forceinline__ void gemm32x256(const unsigned short* A,
                                           const unsigned short* __restrict__ W,
                                           int w, int l, fl4 acc[4][2]) {
    const int qd = l >> 4, c16 = l & 15;
    const unsigned voff = (unsigned)(l * 16);      // per-lane byte offset
    unsigned long long wb = rfl64(W + w * 16384);  // wave-uniform -> SGPR
    unsigned long long bs[8];
#pragma unroll
    for (int ci = 0; ci < 4; ++ci) {
        bs[ci * 2]     = wb + (unsigned)(ci * 8192);
        bs[ci * 2 + 1] = wb + (unsigned)(ci * 8192 + 4096);
    }
    sh8 bfr[4][4], afr[2][2];
    // prologue: pairs 0..2 (12 loads in flight), all half=0
    gls<0>(bfr[0][0], voff, bs[0]); gls<0>(bfr[0][1], voff, bs[2]);
    gls<0>(bfr[0][2], voff, bs[4]); gls<0>(bfr[0][3], voff, bs[6]);
    gls<1024>(bfr[1][0], voff, bs[0]); gls<1024>(bfr[1][1], voff, bs[2]);
    gls<1024>(bfr[1][2], voff, bs[4]); gls<1024>(bfr[1][3], voff, bs[6]);
    gls<2048>(bfr[2][0], voff, bs[0]); gls<2048>(bfr[2][1], voff, bs[2]);
    gls<2048>(bfr[2][2], voff, bs[4]); gls<2048>(bfr[2][3], voff, bs[6]);
#pragma unroll
    for (int rt = 0; rt < 2; ++rt)
        afr[0][rt] = *(const sh8*)(A + EA(rt * 16 + c16, qd * 8));
    gstep<0>(A, qd, c16, voff, bs, bfr, afr, acc);
    gstep<1>(A, qd, c16, voff, bs, bfr, afr, acc);
    gstep<2>(A, qd, c16, voff, bs, bfr, afr, acc);
    gstep<3>(A, qd, c16, voff, bs, bfr, afr, acc);
    gstep<4>(A, qd, c16, voff, bs, bfr, afr, acc);
    gstep<5>(A, qd, c16, voff, bs, bfr, afr, acc);
    gstep<6>(A, qd, c16, voff, bs, bfr, afr, acc);
    gstep<7>(A, qd, c16, voff, bs, bfr, afr, acc);
}

__launch_bounds__(256, 3)
__global__ void fused_kernel(const float* __restrict__ inputs, const float* __restrict__ EC,
                             const float* __restrict__ pos_emb, const float* __restrict__ lin_b,
                             const unsigned short* __restrict__ wsW,
                             float* __restrict__ d_out) {
    extern __shared__ char smem[];
    unsigned short* X = (unsigned short*)smem;   // temporal -> v_T      [32][256] / [256][32]
    unsigned short* Y = X + 8192;                // EC -> k -> P(ST lay) [32][256]
    unsigned short* Z = Y + 8192;                // q -> ctx             [32][256]
    float*       outL = (float*)(Z + 8192);      // [2][256] f32

    const int tid = threadIdx.x;
    const int w = tid >> 6, l = tid & 63;
    const int qd = l >> 4, c16 = l & 15;
    const size_t rbase = (size_t)blockIdx.x * 32;
    const int n0 = blockIdx.x * 2;

    // ---- stage: issue ALL global loads first (one HBM round-trip), then convert ----
    fl4 ins[8], ecs[8], pes[8];
#pragma unroll
    for (int i = 0; i < 8; ++i) {
        size_t g = (rbase + i * 4 + w) * 256 + 4 * l;
        ins[i] = *(const fl4*)(inputs + g);
        ecs[i] = *(const fl4*)(EC + g);
    }
#pragma unroll
    for (int i = 0; i < 8; ++i)
        pes[i] = *(const fl4*)(pos_emb + ((i * 4 + w) & 15) * 256 + 4 * l);

    // zero outL (tmean accumulates via LDS atomics after B1)
    outL[tid] = 0.f;
    outL[256 + tid] = 0.f;

    fl4 tacc0 = {0.f, 0.f, 0.f, 0.f}, tacc1 = {0.f, 0.f, 0.f, 0.f};
#pragma unroll
    for (int i = 0; i < 8; ++i) {
        int row = i * 4 + w;
        fl4 t4 = ins[i] + pes[i];
        if (i < 4) tacc0 += t4; else tacc1 += t4;
        *(uint2*)(X + EA(row, 4 * l)) = make_uint2(cvt2u(t4[0], t4[1]), cvt2u(t4[2], t4[3]));
        *(uint2*)(Y + EA(row, 4 * l)) =
            make_uint2(cvt2u(ecs[i][0], ecs[i][1]), cvt2u(ecs[i][2], ecs[i][3]));
    }
    __syncthreads();                               // B1

    // tmean contribution (rows w,4+w,8+w,12+w -> node0; +16 -> node1)
#pragma unroll
    for (int j = 0; j < 4; ++j) {
        atomicAdd(&outL[4 * l + j], tacc0[j] * 0.0625f);
        atomicAdd(&outL[256 + 4 * l + j], tacc1[j] * 0.0625f);
    }

    // ---- k = EC@Wk (in-place to Y), q = temporal@Wq (to Z) ----
    {
        fl4 aK[4][2] = {}, aQ[4][2] = {};
        gemm32x256(Y, wsW + 65536, w, l, aK);
        gemm32x256(X, wsW, w, l, aQ);
        __syncthreads();                           // B2: all X/Y reads done
#pragma unroll
        for (int ci = 0; ci < 4; ++ci) {
            int col = w * 64 + ci * 16 + c16;
#pragma unroll
            for (int rt = 0; rt < 2; ++rt) {
                int r0 = rt * 16 + qd * 4;
                unsigned int k01 = cvt2u(aK[ci][rt][0], aK[ci][rt][1]);
                unsigned int k23 = cvt2u(aK[ci][rt][2], aK[ci][rt][3]);
                unsigned int q01 = cvt2u(aQ[ci][rt][0], aQ[ci][rt][1]);
                unsigned int q23 = cvt2u(aQ[ci][rt][2], aQ[ci][rt][3]);
                Y[EA(r0 + 0, col)] = (unsigned short)k01;
                Y[EA(r0 + 1, col)] = (unsigned short)(k01 >> 16);
                Y[EA(r0 + 2, col)] = (unsigned short)k23;
                Y[EA(r0 + 3, col)] = (unsigned short)(k23 >> 16);
                Z[EA(r0 + 0, col)] = (unsigned short)q01;
                Z[EA(r0 + 1, col)] = (unsigned short)(q01 >> 16);
                Z[EA(r0 + 2, col)] = (unsigned short)q23;
                Z[EA(r0 + 3, col)] = (unsigned short)(q23 >> 16);
            }
        }
    }
    __syncthreads();                               // B3: k,q ready

    // ---- QK^T transposed: st[h] = K @ Q^T -> lane holds S[qt=c16][kt=qd*4+i2] ----
    const int nd = w >> 1, hb = (w & 1) * 8;
    fl4 st[8];
#pragma unroll
    for (int h = 0; h < 8; ++h) {
        sh8 ka = {}, qa = {};
        if (l < 32) {                              // d-dim K=16 padded to 32
            ka = *(const sh8*)(Y + EA(nd * 16 + c16, (hb + h) * 16 + qd * 8));
            qa = *(const sh8*)(Z + EA(nd * 16 + c16, (hb + h) * 16 + qd * 8));
        }
        fl4 z = {};
        st[h] = __builtin_amdgcn_mfma_f32_16x16x32_bf16(ka, qa, z, 0, 0, 0);
    }

    // ---- v = temporal@Wv (overlaps softmax below) ----
    fl4 aV[4][2] = {};
    gemm32x256(X, wsW + 131072, w, l, aV);

    // ---- softmax over kt: 3 in-lane adds + 2 shfl; no max-subtract (f32 exp headroom) ----
#pragma unroll
    for (int h = 0; h < 8; ++h) {
        fl4 e;
#pragma unroll
        for (int i2 = 0; i2 < 4; ++i2)
            e[i2] = __builtin_amdgcn_exp2f(st[h][i2] * 0.36067376022f);  // exp(s*0.25)
        float sum = e[0] + e[1] + e[2] + e[3];
        sum += __shfl_xor(sum, 16);
        sum += __shfl_xor(sum, 32);
        float r = __builtin_amdgcn_rcpf(sum);
        // P in ST layout: row = node*16+qt, cols h*16 + qd*4 + i2 (contiguous 4)
        *(uint2*)(Y + EA(nd * 16 + c16, (hb + h) * 16 + qd * 4)) =
            make_uint2(cvt2u(e[0] * r, e[1] * r), cvt2u(e[2] * r, e[3] * r));
    }
    __syncthreads();                               // B4: X reads (v GEMM) done, P written

    // ---- v_T -> X (t contiguous per i2 -> uint2 stores) ----
#pragma unroll
    for (int ci = 0; ci < 4; ++ci) {
        int col = w * 64 + ci * 16 + c16;
#pragma unroll
        for (int rt = 0; rt < 2; ++rt) {
            int t0 = rt * 16 + qd * 4;
            *(uint2*)(X + EV(col, t0)) =
                make_uint2(cvt2u(aV[ci][rt][0], aV[ci][rt][1]),
                           cvt2u(aV[ci][rt][2], aV[ci][rt][3]));
        }
    }
    __syncthreads();                               // B5: P, v_T ready

    // ---- PV: ctx -> Z (q dead); ctx-mean via shfl-reduce (was 4-way LDS atomic) ----
#pragma unroll
    for (int h = 0; h < 8; ++h) {
        sh8 pa = {};
        if (l < 32)                                // kt 16..31 pad = zero
            pa = *(const sh8*)(Y + EA(nd * 16 + c16, (hb + h) * 16 + qd * 8));
        sh8 vb = *(const sh8*)(X + EV((hb + h) * 16 + c16, nd * 16 + (qd & 1) * 8));
        fl4 z = {};
        fl4 cx = __builtin_amdgcn_mfma_f32_16x16x32_bf16(pa, vb, z, 0, 0, 0);
        int col = (hb + h) * 16 + c16;
        unsigned int c01 = cvt2u(cx[0], cx[1]);
        unsigned int c23 = cvt2u(cx[2], cx[3]);
        int r0 = nd * 16 + qd * 4;
        Z[EA(r0 + 0, col)] = (unsigned short)c01;
        Z[EA(r0 + 1, col)] = (unsigned short)(c01 >> 16);
        Z[EA(r0 + 2, col)] = (unsigned short)c23;
        Z[EA(r0 + 3, col)] = (unsigned short)(c23 >> 16);
        // lanes {l, l^16, l^32, l^48} hold the 4 qd row-groups of the same col:
        float ssum = (cx[0] + cx[1] + cx[2] + cx[3]) * 0.0625f;
        ssum += __shfl_xor(ssum, 16);
        ssum += __shfl_xor(ssum, 32);
        if (l < 16) outL[nd * 256 + col] += ssum;  // col range is wave-exclusive
    }

    // ---- ST dump: Y is [node][qt][h*16+kt] => coalesced fl4 stores ----
#pragma unroll
    for (int ch = 0; ch < 8; ++ch) {
        int flat = ch * 1024 + tid * 4;
        int row = flat >> 8, col = flat & 255;
        sh4 pv = *(const sh4*)(Y + (row << 8) + (col ^ ((row & 7) << 3)));
        fl4 o;
#pragma unroll
        for (int j = 0; j < 4; ++j) o[j] = bf2f((unsigned short)pv[j]);
        *(fl4*)(d_out + OUT0 + (size_t)blockIdx.x * 8192 + flat) = o;
    }
    __syncthreads();                               // B6: ctx(Z) ready

    // ---- ff = relu(ctx@lin_w^T + b); mean over T into outL (ctx-mean already added) ----
    {
        fl4 aF[4][2] = {};
        gemm32x256(Z, wsW + 196608, w, l, aF);
#pragma unroll
        for (int ci = 0; ci < 4; ++ci) {
            int col = w * 64 + ci * 16 + c16;
            float bias = lin_b[col];
#pragma unroll
            for (int rt = 0; rt < 2; ++rt) {
                float ssum = 0.f;
#pragma unroll
                for (int i2 = 0; i2 < 4; ++i2)
                    ssum += fmaxf(aF[ci][rt][i2] + bias, 0.f);
                ssum += __shfl_xor(ssum, 16);      // sum 4 qd row-groups -> all 16 t
                ssum += __shfl_xor(ssum, 32);
                if (l < 16) outL[rt * 256 + col] += ssum * 0.0625f;
            }
        }
    }
    __syncthreads();                               // B7

    // ---- write out[n][c] ----
    if (tid < 128) {
        int idx = tid * 4;
        fl4 o = *(const fl4*)(outL + idx);
        *(fl4*)(d_out + (size_t)n0 * 256 + idx) = o;
    }
}

extern "C" void kernel_launch(void* const* d_in, const int* in_sizes, int n_in,
                              void* d_out, int out_size, void* d_ws, size_t ws_size,
                              hipStream_t stream) {
    const float* inputs = (const float*)d_in[0];
    const float* EC     = (const float*)d_in[1];
    const float* pos    = (const float*)d_in[2];
    const float* Wq     = (const float*)d_in[3];
    const float* Wk     = (const float*)d_in[4];
    const float* Wv     = (const float*)d_in[5];
    const float* lw     = (const float*)d_in[6];
    const float* lb     = (const float*)d_in[7];
    unsigned short* wsW = (unsigned short*)d_ws;   // 4 x 65536 bf16 = 512 KB
    float* out = (float*)d_out;

    (void)hipFuncSetAttribute(reinterpret_cast<const void*>(fused_kernel),
                              hipFuncAttributeMaxDynamicSharedMemorySize, 51200);

    setup_kernel<<<256, 256, 0, stream>>>(Wq, Wk, Wv, lw, wsW);
    fused_kernel<<<16384, 256, 51200, stream>>>(inputs, EC, pos, lb, wsW, out);
}